// Round 8
// baseline (3251.633 us; speedup 1.0000x reference)
//
#include <hip/hip_runtime.h>
#include <hip/hip_fp16.h>

// Sinkhorn OT: 64 chains, d=768, lam=0.01, 100 iters + final LSE.
// Round 8: fused-word exchange at PROVEN agent scope (no XCD assumptions).
//  - One 8B word per (element,part): {S:fp32 | cu:fp16 | tag:u16}. Tag==hs
//    is the readiness flag; cu is the poster's e-offset (fp16-rounded BEFORE
//    use, so reconstruction is exact). Eliminates round 6's flag stores,
//    vmcnt+barrier in post, 64x8 flag poll storms, and the second MALL trip.
//  - Posts are fire-and-forget; gather = one bounded poll per lane.
//  - Parity double-buffer (h vs h+1 overwrite race); h+2 reuse safe since
//    post(h+2) transitively follows all gathers(h). 0xAA poison tag=43690
//    never matches real tags 1..202 => re-poison safe.
//  - Keeps: reduce-scatter (block owns 96 rows AND 96 cols), static B&7
//    grouping, 2-chain stagger, fp16 K x fp32 e matvec, bounded spins.

#define D        768
#define SEG      96
#define QP       12
#define NITERS   100
#define INV_LAM  100.0f
#define C14      9.70406052784f   // 14*ln2 (2^14 fp16 scale folded into offsets)
#define SCALE14  16384.0f
#define LOG768   6.64385618977f
#define SPIN_CAP 2048             // ~1.4ms cap; expected waits <10us

typedef unsigned long long ull;

// ---- fp16 offset helpers (round-then-use => exact reconstruction) ----
static __device__ __forceinline__ unsigned h_bits(float x) {
    return (unsigned)__half_as_ushort(__float2half(x));
}
static __device__ __forceinline__ float h_val(unsigned b) {
    return __half2float(__ushort_as_half((unsigned short)b));
}

// ---- fused exchange word: [tag:16 | cu_fp16:16 | S:fp32] ----
static __device__ __forceinline__ void post_word(ull* p, float S, unsigned cub, int tag) {
    ull w = ((ull)((((unsigned)tag) << 16) | cub) << 32) | (ull)__float_as_uint(S);
    __hip_atomic_store(p, w, __ATOMIC_RELAXED, __HIP_MEMORY_SCOPE_AGENT);
}
static __device__ __forceinline__ ull poll_word(const ull* p, int tag) {
    ull w = __hip_atomic_load((ull*)p, __ATOMIC_RELAXED, __HIP_MEMORY_SCOPE_AGENT);
    int spin = SPIN_CAP;
    while ((unsigned)(w >> 48) != (unsigned)tag && --spin) {
        __builtin_amdgcn_s_sleep(1);
        w = __hip_atomic_load((ull*)p, __ATOMIC_RELAXED, __HIP_MEMORY_SCOPE_AGENT);
    }
    return w;
}

// ---- partial matvec: out[tid] = sum over 96 local elems (12 quads) ----
static __device__ __forceinline__ float mv_part(const uint4* __restrict__ mp,
                                                const float* __restrict__ ef) {
    const float4* e4 = (const float4*)ef;
    float a0 = 0.f, a1 = 0.f, a2 = 0.f, a3 = 0.f;
    #pragma unroll
    for (int t = 0; t < QP; ++t) {
        uint4 kv = mp[(size_t)t * D];
        float4 x = e4[2 * t];
        float4 y = e4[2 * t + 1];
        float2 k0 = __half22float2(__builtin_bit_cast(__half2, kv.x));
        float2 k1 = __half22float2(__builtin_bit_cast(__half2, kv.y));
        float2 k2 = __half22float2(__builtin_bit_cast(__half2, kv.z));
        float2 k3 = __half22float2(__builtin_bit_cast(__half2, kv.w));
        a0 = fmaf(k0.x, x.x, a0); a1 = fmaf(k0.y, x.y, a1);
        a2 = fmaf(k1.x, x.z, a2); a3 = fmaf(k1.y, x.w, a3);
        a0 = fmaf(k2.x, y.x, a0); a1 = fmaf(k2.y, y.y, a1);
        a2 = fmaf(k3.x, y.z, a2); a3 = fmaf(k3.y, y.w, a3);
    }
    return (a0 + a1) + (a2 + a3);
}

// ---- gather core: poll own (part,elem) word; 8-lane logsum (cu's cancel) ----
static __device__ __forceinline__ float gather_logsum_f(const ull* xr, int tag) {
    ull w = poll_word(xr, tag);
    float S = __uint_as_float((unsigned)w);
    float cu = h_val((unsigned)(w >> 32) & 0xffffu);
    float cs = cu;
    #pragma unroll
    for (int o = 1; o < 8; o <<= 1) cs = fmaxf(cs, __shfl_xor(cs, o));
    float t = S * __expf(cu - cs);
    #pragma unroll
    for (int o = 1; o < 8; o <<= 1) t += __shfl_xor(t, o);
    return __logf(t) + cs;
}

// ---- gather: new log-vec at own 96 idx, fp16-rounded local max, e -> LDS ----
static __device__ __forceinline__ void gather_step_f(const ull* xr, int tag,
                                                     float logmn, float coffj, int tid,
                                                     float* s_red, float* e_out,
                                                     float& lx_o, unsigned& cb_o) {
    float lx = logmn - (gather_logsum_f(xr, tag) + coffj);
    float m = lx;
    #pragma unroll
    for (int o = 8; o < 64; o <<= 1) m = fmaxf(m, __shfl_xor(m, o));
    if ((tid & 63) == 0) s_red[tid >> 6] = m;
    __syncthreads();
    float mm = s_red[0];
    #pragma unroll
    for (int w = 1; w < 12; ++w) mm = fmaxf(mm, s_red[w]);
    unsigned mb = h_bits(mm);                   // round FIRST...
    float mf = h_val(mb);                       // ...then use rounded value
    float e = __expf(lx - mf);                  // computed by ALL lanes
    if ((tid & 7) == 0) e_out[tid >> 3] = e;    // plain per-lane store
    lx_o = lx; cb_o = mb;
    __syncthreads();
}

// ---- LSE over own 96 -> (m_fp16rounded, z) ----
static __device__ __forceinline__ float2 lse96h(float negs, float* s_red, int tid,
                                                unsigned& mb_o) {
    int pp = tid & 7;
    float m = negs;
    #pragma unroll
    for (int o = 8; o < 64; o <<= 1) m = fmaxf(m, __shfl_xor(m, o));
    __syncthreads();
    if ((tid & 63) == 0) s_red[tid >> 6] = m;
    __syncthreads();
    float mm = s_red[0];
    #pragma unroll
    for (int w = 1; w < 12; ++w) mm = fmaxf(mm, s_red[w]);
    unsigned mb = h_bits(mm);
    float mf = h_val(mb);
    float zv = (pp == 0) ? __expf(negs - mf) : 0.f;
    #pragma unroll
    for (int o = 1; o < 64; o <<= 1) zv += __shfl_xor(zv, o);
    __syncthreads();
    if ((tid & 63) == 0) s_red[tid >> 6] = zv;
    __syncthreads();
    float z = s_red[0];
    #pragma unroll
    for (int w = 1; w < 12; ++w) z += s_red[w];
    mb_o = mb;
    return make_float2(mf, z);
}

// ---- prep: fp16 K-hat (per-column offsets) ----
__global__ void prep_cols(const float* __restrict__ dist, uint4* __restrict__ Kq,
                          float* __restrict__ cK2, float* __restrict__ cF2) {
    int T = blockIdx.x * blockDim.x + threadIdx.x;
    int j = T >> 3, w = T & 7;
    float mc = 3.402823e38f, mf = -3.402823e38f;
    for (int i = 96 * w; i < 96 * w + 96; ++i) {
        float d = dist[(size_t)i * D + j];
        mc = fminf(mc, d);
        mf = fmaxf(mf, __logf(d) - d * INV_LAM);
    }
    #pragma unroll
    for (int o = 1; o < 8; o <<= 1) { mc = fminf(mc, __shfl_xor(mc, o)); mf = fmaxf(mf, __shfl_xor(mf, o)); }
    if (w == 0) { cK2[j] = -mc * INV_LAM - C14; cF2[j] = mf; }
    for (int t = 0; t < QP; ++t) {
        int q = QP * w + t;
        union { uint4 u4; __half2 h2[8]; } pk;
        #pragma unroll
        for (int r = 0; r < 4; ++r) {
            float d0 = dist[(size_t)(8 * q + 2 * r) * D + j];
            float d1 = dist[(size_t)(8 * q + 2 * r + 1) * D + j];
            pk.h2[r] = __halves2half2(__float2half(__expf((mc - d0) * INV_LAM) * SCALE14),
                                      __float2half(__expf((mc - d1) * INV_LAM) * SCALE14));
        }
        Kq[(size_t)q * D + j] = pk.u4;
    }
}

// ---- prep: fp16 K^T-hat (per-row offsets) ----
__global__ void prep_rows(const float* __restrict__ dist, uint4* __restrict__ KTq,
                          float* __restrict__ cKT2) {
    int T = blockIdx.x * blockDim.x + threadIdx.x;
    int i = T >> 3, w = T & 7;
    const float* row = dist + (size_t)i * D;
    float mr = 3.402823e38f;
    for (int jj = 96 * w; jj < 96 * w + 96; ++jj) mr = fminf(mr, row[jj]);
    #pragma unroll
    for (int o = 1; o < 8; o <<= 1) mr = fminf(mr, __shfl_xor(mr, o));
    if (w == 0) cKT2[i] = -mr * INV_LAM - C14;
    for (int t = 0; t < QP; ++t) {
        int q = QP * w + t;
        union { uint4 u4; __half2 h2[8]; } pk;
        #pragma unroll
        for (int r = 0; r < 4; ++r) {
            float d0 = row[8 * q + 2 * r];
            float d1 = row[8 * q + 2 * r + 1];
            pk.h2[r] = __halves2half2(__float2half(__expf((mr - d0) * INV_LAM) * SCALE14),
                                      __float2half(__expf((mr - d1) * INV_LAM) * SCALE14));
        }
        KTq[(size_t)q * D + i] = pk.u4;
    }
}

// ---- main: 32 groups x 8 parts (static B&7 grouping), 2 staggered chains ----
__global__ __launch_bounds__(768) void sink8(
    const float* __restrict__ mu, const float* __restrict__ nu,
    const float* __restrict__ dist,
    const uint4* __restrict__ Kq, const uint4* __restrict__ KTq,
    const float* __restrict__ cK2, const float* __restrict__ cKT2,
    const float* __restrict__ cF2,
    ull* __restrict__ xbuf, ull* __restrict__ fw,
    float* __restrict__ out) {
    __shared__ __align__(16) float s_eu[2][SEG];   // e^{lu - cu_loc}, fp32
    __shared__ __align__(16) float s_ev[2][SEG];   // e^{lv - cv_loc}, fp32
    __shared__ float s_red[12];
    __shared__ char s_pad[81920];   // LDS > 80KB => 1 block/CU => all 256 resident
    if (mu == nullptr) { s_pad[threadIdx.x] = 1; s_eu[0][0] = (float)s_pad[0]; }

    const int tid = threadIdx.x;
    const int B = blockIdx.x;
    const int x = B & 7, s = B >> 3;
    const int g = x * 4 + (s >> 3);                 // group 0..31
    const int p = s & 7;                            // part 0..7
    const int c0 = 2 * g;
    const int pp = tid & 7, jj = tid >> 3;
    const int jglob = p * SEG + jj;

    const float lnu0 = __logf(nu[(size_t)c0 * D + jglob]);
    const float lnu1 = __logf(nu[(size_t)(c0 + 1) * D + jglob]);
    const float lmu0 = __logf(mu[(size_t)c0 * D + jglob]);
    const float lmu1 = __logf(mu[(size_t)(c0 + 1) * D + jglob]);
    const float cKg = cK2[jglob], cKTg = cKT2[jglob], cFg = cF2[jglob];
    const float cFt = cF2[tid];

    const uint4* Kv = Kq  + (size_t)(QP * p) * D + tid;   // own 96 rows (v-step)
    const uint4* Ku = KTq + (size_t)(QP * p) * D + tid;   // own 96 cols (u-step)

    // fused-word regions: region (chain*2 + parity), word [part*768 + elem]
    ull* const xw0e = xbuf + (size_t)(c0 * 2 + 0) * 6144 + p * 768 + tid;
    ull* const xw0o = xbuf + (size_t)(c0 * 2 + 1) * 6144 + p * 768 + tid;
    ull* const xw1e = xbuf + (size_t)((c0 + 1) * 2 + 0) * 6144 + p * 768 + tid;
    ull* const xw1o = xbuf + (size_t)((c0 + 1) * 2 + 1) * 6144 + p * 768 + tid;
    const ull* const xr0e = xbuf + (size_t)(c0 * 2 + 0) * 6144 + pp * 768 + jglob;
    const ull* const xr0o = xbuf + (size_t)(c0 * 2 + 1) * 6144 + pp * 768 + jglob;
    const ull* const xr1e = xbuf + (size_t)((c0 + 1) * 2 + 0) * 6144 + pp * 768 + jglob;
    const ull* const xr1o = xbuf + (size_t)((c0 + 1) * 2 + 1) * 6144 + pp * 768 + jglob;

    // init: lu = -log768 -> offset = fp16(-log768), e = exp(lu - offset)
    unsigned r_cb0 = h_bits(-LOG768), r_cb1 = r_cb0;
    {
        float e0 = __expf(-LOG768 - h_val(r_cb0));
        if (tid < SEG) { s_eu[0][tid] = e0; s_eu[1][tid] = e0; }
    }
    float r_lv0 = 0.f, r_lv1 = 0.f, r_dump;
    unsigned cbv0, cbv1;
    int hs0 = 0, hs1 = 0;
    __syncthreads();

    for (int it = 0; it < NITERS; ++it) {
        // A: v matvec + post
        float SA = mv_part(Kv, s_eu[0]);
        ++hs0;
        post_word((hs0 & 1) ? xw0o : xw0e, SA, r_cb0, hs0);
        // B: u gather from previous iteration (hides A's fabric latency)
        if (it > 0) {
            gather_step_f((hs1 & 1) ? xr1o : xr1e, hs1, lmu1, cKTg, tid,
                          s_red, s_eu[1], r_dump, r_cb1);
        }
        // B: v matvec + post
        float SB = mv_part(Kv, s_eu[1]);
        ++hs1;
        post_word((hs1 & 1) ? xw1o : xw1e, SB, r_cb1, hs1);
        // A: v gather
        gather_step_f((hs0 & 1) ? xr0o : xr0e, hs0, lnu0, cKg, tid,
                      s_red, s_ev[0], r_lv0, cbv0);
        // A: u matvec + post
        float TA = mv_part(Ku, s_ev[0]);
        ++hs0;
        post_word((hs0 & 1) ? xw0o : xw0e, TA, cbv0, hs0);
        // B: v gather
        gather_step_f((hs1 & 1) ? xr1o : xr1e, hs1, lnu1, cKg, tid,
                      s_red, s_ev[1], r_lv1, cbv1);
        // B: u matvec + post
        float TB = mv_part(Ku, s_ev[1]);
        ++hs1;
        post_word((hs1 & 1) ? xw1o : xw1e, TB, cbv1, hs1);
        // A: u gather
        gather_step_f((hs0 & 1) ? xr0o : xr0e, hs0, lmu0, cKTg, tid,
                      s_red, s_eu[0], r_dump, r_cb0);
    }
    // B: final u gather (tag 200, even parity)
    gather_step_f((hs1 & 1) ? xr1o : xr1e, hs1, lmu1, cKTg, tid,
                  s_red, s_eu[1], r_dump, r_cb1);

    // final partials: F-hat computed on the fly (fp32), both chains
    float FA = 0.f, FB = 0.f;
    const float* dp = dist + (size_t)(SEG * p) * D + tid;
    #pragma unroll 4
    for (int ii = 0; ii < SEG; ++ii) {
        float d = dp[(size_t)ii * D];
        float fh = __expf(__logf(d) - d * INV_LAM - cFt);
        FA = fmaf(fh, s_eu[0][ii], FA);
        FB = fmaf(fh, s_eu[1][ii], FB);
    }
    ++hs0;
    post_word((hs0 & 1) ? xw0o : xw0e, FA, r_cb0, hs0);   // tag 201
    ++hs1;
    post_word((hs1 & 1) ? xw1o : xw1e, FB, r_cb1, hs1);

    float negs0 = r_lv0 + gather_logsum_f((hs0 & 1) ? xr0o : xr0e, hs0) + cFg;
    unsigned mbA;
    float2 mzA = lse96h(negs0, s_red, tid, mbA);
    float negs1 = r_lv1 + gather_logsum_f((hs1 & 1) ? xr1o : xr1e, hs1) + cFg;
    unsigned mbB;
    float2 mzB = lse96h(negs1, s_red, tid, mbB);

    // per-part (m,z) fused words (tag 202) -> combine at part 0
    if (tid == 0) {
        post_word(&fw[(size_t)(g * 8 + p) * 2 + 0], mzA.y, mbA, 202);
        post_word(&fw[(size_t)(g * 8 + p) * 2 + 1], mzB.y, mbB, 202);
    }
    if (p == 0 && tid < 16) {
        int ch = tid >> 3;                  // 0: chain c0, 1: chain c0+1
        int q = tid & 7;                    // source part
        ull w = poll_word(&fw[(size_t)(g * 8 + q) * 2 + ch], 202);
        float z = __uint_as_float((unsigned)w);
        float mh = h_val((unsigned)(w >> 32) & 0xffffu);
        float ms = mh;
        #pragma unroll
        for (int o = 1; o < 8; o <<= 1) ms = fmaxf(ms, __shfl_xor(ms, o));  // octet-local
        float zz = z * __expf(mh - ms);
        #pragma unroll
        for (int o = 1; o < 8; o <<= 1) zz += __shfl_xor(zz, o);
        if (q == 0) out[c0 + ch] = __expf(ms) * zz;
    }
}

extern "C" void kernel_launch(void* const* d_in, const int* in_sizes, int n_in,
                              void* d_out, int out_size, void* d_ws, size_t ws_size,
                              hipStream_t stream) {
    const float* mu   = (const float*)d_in[0];
    const float* nu   = (const float*)d_in[1];
    const float* dist = (const float*)d_in[2];
    float* out = (float*)d_out;
    (void)in_sizes; (void)n_in; (void)out_size; (void)ws_size;

    char* w8 = (char*)d_ws;                       // ~8.67 MB total
    uint4* Kq   = (uint4*)(w8);                   // 1,179,648
    uint4* KTq  = (uint4*)(w8 + 1179648);         // 1,179,648
    float* cK2  = (float*)(w8 + 2359296);         // 3072
    float* cKT2 = (float*)(w8 + 2362368);         // 3072
    float* cF2  = (float*)(w8 + 2365440);         // 3072
    ull*   xbuf = (ull*)  (w8 + 2368512);         // 6,291,456 (128 regions x 6144 x 8B)
    ull*   fw   = (ull*)  (w8 + 8659968);         // 4096

    prep_cols<<<24, 256, 0, stream>>>(dist, Kq, cK2, cF2);
    prep_rows<<<24, 256, 0, stream>>>(dist, KTq, cKT2);
    sink8<<<256, 768, 0, stream>>>(mu, nu, dist, Kq, KTq, cK2, cKT2, cF2,
                                   xbuf, fw, out);
}

// Round 9
// 1981.950 us; speedup vs baseline: 1.6406x; 1.6406x over previous
//
#include <hip/hip_runtime.h>
#include <hip/hip_fp16.h>

// Sinkhorn OT: 64 chains, d=768, lam=0.01, 100 iters + final LSE.
// Round 9: EXCHANGE-FREE topology (round-1 structure) + round-2-proven
// numerics. Measured lesson (rounds 2/6/8): agent-scope exchange is MALL-
// coherent on MI355X -> 7-16us/half-step + GBs of HBM poll traffic; any
// cross-block dependency costs more than the matvec it parallelizes.
// Design: one persistent 768-thread block per chain (64 blocks), only
// __syncthreads(); fp16 K/KT/F-hat x2^14 (offsets fold -14ln2), fp32 e in
// LDS (validated in rounds 2,6,8); K+KT+F (3.5MB) stay XCD-L2-resident.

#define D        768
#define NQ       96              // D/8 quads (8 fp16 rows per uint4)
#define NITERS   100
#define INV_LAM  100.0f
#define C14      9.70406052784f  // 14*ln2 (2^14 fp16 scale folded into offsets)
#define SCALE14  16384.0f
#define LOG768   6.64385618977f

// ---- block reductions over 768 threads (12 waves) ----
static __device__ __forceinline__ float block_max(float v, float* red, int tid) {
    #pragma unroll
    for (int o = 32; o; o >>= 1) v = fmaxf(v, __shfl_xor(v, o));
    __syncthreads();                    // also orders prior s_e readers vs overwrite
    if ((tid & 63) == 0) red[tid >> 6] = v;
    __syncthreads();
    float m = red[0];
    #pragma unroll
    for (int w = 1; w < 12; ++w) m = fmaxf(m, red[w]);
    return m;
}
static __device__ __forceinline__ float block_sum(float v, float* red, int tid) {
    #pragma unroll
    for (int o = 32; o; o >>= 1) v += __shfl_xor(v, o);
    __syncthreads();
    if ((tid & 63) == 0) red[tid >> 6] = v;
    __syncthreads();
    float s = red[0];
    #pragma unroll
    for (int w = 1; w < 12; ++w) s += red[w];
    return s;
}

// ---- matvec: S[tid] = sum_i M[i,tid] * e[i]; M = fp16 pairs, e = fp32 LDS ----
// Quad q of column j at mp[q*D]; lane-consecutive 16B loads (coalesced);
// e reads are wave-uniform LDS broadcasts (conflict-free). fpext(half) ops
// fold into v_fma_mix_f32 on gfx9+.
static __device__ __forceinline__ float mv(const uint4* __restrict__ mp,
                                           const float* __restrict__ ef) {
    const float4* e4 = (const float4*)ef;
    float a0 = 0.f, a1 = 0.f, a2 = 0.f, a3 = 0.f;
    #pragma unroll 4
    for (int q = 0; q < NQ; ++q) {
        uint4 kv = mp[(size_t)q * D];
        float4 x = e4[2 * q];
        float4 y = e4[2 * q + 1];
        float2 k0 = __half22float2(__builtin_bit_cast(__half2, kv.x));
        float2 k1 = __half22float2(__builtin_bit_cast(__half2, kv.y));
        float2 k2 = __half22float2(__builtin_bit_cast(__half2, kv.z));
        float2 k3 = __half22float2(__builtin_bit_cast(__half2, kv.w));
        a0 = fmaf(k0.x, x.x, a0); a1 = fmaf(k0.y, x.y, a1);
        a2 = fmaf(k1.x, x.z, a2); a3 = fmaf(k1.y, x.w, a3);
        a0 = fmaf(k2.x, y.x, a0); a1 = fmaf(k2.y, y.y, a1);
        a2 = fmaf(k3.x, y.z, a2); a3 = fmaf(k3.y, y.w, a3);
    }
    return (a0 + a1) + (a2 + a3);
}

// ---- prep: fp16 K-hat and F-hat (per-column offsets) ----
// 6144 threads: 8 workers (w) per column j; column min/max reduced across
// workers via shfl BEFORE packing.
__global__ void prep_cols(const float* __restrict__ dist, uint4* __restrict__ Kq,
                          uint4* __restrict__ Fq, float* __restrict__ cK2,
                          float* __restrict__ cF2) {
    int T = blockIdx.x * blockDim.x + threadIdx.x;
    int j = T >> 3, w = T & 7;
    float mc = 3.402823e38f, mf = -3.402823e38f;
    for (int i = 96 * w; i < 96 * w + 96; ++i) {
        float d = dist[(size_t)i * D + j];
        mc = fminf(mc, d);
        mf = fmaxf(mf, __logf(d) - d * INV_LAM);
    }
    #pragma unroll
    for (int o = 1; o < 8; o <<= 1) {
        mc = fminf(mc, __shfl_xor(mc, o));
        mf = fmaxf(mf, __shfl_xor(mf, o));
    }
    if (w == 0) { cK2[j] = -mc * INV_LAM - C14; cF2[j] = mf - C14; }
    for (int t = 0; t < 12; ++t) {
        int q = 12 * w + t;
        union { uint4 u4; __half2 h2[8]; } pk, pf;
        #pragma unroll
        for (int r = 0; r < 4; ++r) {
            float d0 = dist[(size_t)(8 * q + 2 * r) * D + j];
            float d1 = dist[(size_t)(8 * q + 2 * r + 1) * D + j];
            pk.h2[r] = __halves2half2(
                __float2half(__expf((mc - d0) * INV_LAM) * SCALE14),
                __float2half(__expf((mc - d1) * INV_LAM) * SCALE14));
            pf.h2[r] = __halves2half2(
                __float2half(__expf(__logf(d0) - d0 * INV_LAM - mf) * SCALE14),
                __float2half(__expf(__logf(d1) - d1 * INV_LAM - mf) * SCALE14));
        }
        Kq[(size_t)q * D + j] = pk.u4;
        Fq[(size_t)q * D + j] = pf.u4;
    }
}

// ---- prep: fp16 K^T-hat (per-row offsets) ----
__global__ void prep_rows(const float* __restrict__ dist, uint4* __restrict__ KTq,
                          float* __restrict__ cKT2) {
    int T = blockIdx.x * blockDim.x + threadIdx.x;
    int i = T >> 3, w = T & 7;
    const float* row = dist + (size_t)i * D;
    float mr = 3.402823e38f;
    for (int jj = 96 * w; jj < 96 * w + 96; ++jj) mr = fminf(mr, row[jj]);
    #pragma unroll
    for (int o = 1; o < 8; o <<= 1) mr = fminf(mr, __shfl_xor(mr, o));
    if (w == 0) cKT2[i] = -mr * INV_LAM - C14;
    for (int t = 0; t < 12; ++t) {
        int q = 12 * w + t;
        union { uint4 u4; __half2 h2[8]; } pk;
        #pragma unroll
        for (int r = 0; r < 4; ++r) {
            float d0 = row[8 * q + 2 * r];
            float d1 = row[8 * q + 2 * r + 1];
            pk.h2[r] = __halves2half2(
                __float2half(__expf((mr - d0) * INV_LAM) * SCALE14),
                __float2half(__expf((mr - d1) * INV_LAM) * SCALE14));
        }
        KTq[(size_t)q * D + i] = pk.u4;
    }
}

// ---- main: one persistent block per chain; zero cross-block traffic ----
__global__ __launch_bounds__(768) void sink9(
    const float* __restrict__ mu, const float* __restrict__ nu,
    const uint4* __restrict__ Kq, const uint4* __restrict__ KTq,
    const uint4* __restrict__ Fq, const float* __restrict__ cK2,
    const float* __restrict__ cKT2, const float* __restrict__ cF2,
    float* __restrict__ out) {
    __shared__ __align__(16) float s_e[D];
    __shared__ float s_red[16];
    const int tid = threadIdx.x;
    const int b = blockIdx.x;

    const float r_lmu = __logf(mu[(size_t)b * D + tid]);
    const float r_lnu = __logf(nu[(size_t)b * D + tid]);
    const float r_cK = cK2[tid], r_cKT = cKT2[tid], r_cF = cF2[tid];
    const uint4* Kp  = Kq  + tid;
    const uint4* KTp = KTq + tid;
    const uint4* Fp  = Fq  + tid;

    float lu = -LOG768;
    float lv = 0.f;

    for (int it = 0; it < NITERS; ++it) {
        // v-step: log_v[j] = log_nu[j] - (log S'_j + cK2_j + cu)
        float cu = block_max(lu, s_red, tid);   // 1st sync orders prior s_e reads
        s_e[tid] = __expf(lu - cu);
        __syncthreads();
        float S = mv(Kp, s_e);
        lv = r_lnu - (__logf(S) + r_cK + cu);

        // u-step: log_u[i] = log_mu[i] - (log T'_i + cKT2_i + cv)
        float cv = block_max(lv, s_red, tid);
        s_e[tid] = __expf(lv - cv);
        __syncthreads();
        float T = mv(KTp, s_e);
        lu = r_lmu - (__logf(T) + r_cKT + cv);
    }

    // final: -s[j] = lv[j] + log SF'_j + cF2_j + cu ; out = exp(LSE_j(-s))
    float cu = block_max(lu, s_red, tid);
    s_e[tid] = __expf(lu - cu);
    __syncthreads();
    float SF = mv(Fp, s_e);
    float negs = lv + __logf(SF) + r_cF + cu;

    float m = block_max(negs, s_red, tid);
    float z = block_sum(__expf(negs - m), s_red, tid);
    if (tid == 0) out[b] = __expf(m) * z;
}

extern "C" void kernel_launch(void* const* d_in, const int* in_sizes, int n_in,
                              void* d_out, int out_size, void* d_ws, size_t ws_size,
                              hipStream_t stream) {
    const float* mu   = (const float*)d_in[0];
    const float* nu   = (const float*)d_in[1];
    const float* dist = (const float*)d_in[2];
    float* out = (float*)d_out;
    (void)in_sizes; (void)n_in; (void)out_size; (void)ws_size;

    char* w8 = (char*)d_ws;                       // ~3.55 MB total
    uint4* Kq   = (uint4*)(w8);                   // 1,179,648 B
    uint4* KTq  = (uint4*)(w8 + 1179648);         // 1,179,648 B
    uint4* Fq   = (uint4*)(w8 + 2359296);         // 1,179,648 B
    float* cK2  = (float*)(w8 + 3538944);         // 3072 B
    float* cKT2 = (float*)(w8 + 3542016);         // 3072 B
    float* cF2  = (float*)(w8 + 3545088);         // 3072 B

    prep_cols<<<24, 256, 0, stream>>>(dist, Kq, Fq, cK2, cF2);
    prep_rows<<<24, 256, 0, stream>>>(dist, KTq, cKT2);
    sink9<<<64, 768, 0, stream>>>(mu, nu, Kq, KTq, Fq, cK2, cKT2, cF2, out);
}